// Round 1
// baseline (446.254 us; speedup 1.0000x reference)
//
#include <hip/hip_runtime.h>
#include <hip/hip_bf16.h>
#include <float.h>
#include <stdint.h>

typedef __bf16 bf16x8 __attribute__((ext_vector_type(8)));
typedef __bf16 bf16x4 __attribute__((ext_vector_type(4)));
typedef float  f32x4  __attribute__((ext_vector_type(4)));

#define T_SEQ 4096
#define DMODEL 512
#define NH 8
#define HDIM 64

// ---------------------------------------------------------------------------
// Kernel 1: fused QKV projection.  out = X @ W^T + b, stored as bf16.
// Tile: 64x64 per workgroup (4 waves, each 16 rows), K stepped by 64.
// ---------------------------------------------------------------------------
__global__ __launch_bounds__(256) void qkv_kernel(
    const float* __restrict__ qin, const float* __restrict__ kin, const float* __restrict__ vin,
    const float* __restrict__ Wq, const float* __restrict__ bq,
    const float* __restrict__ Wk, const float* __restrict__ bk,
    const float* __restrict__ Wv, const float* __restrict__ bv,
    __bf16* __restrict__ qo, __bf16* __restrict__ ko, __bf16* __restrict__ vo)
{
    __shared__ char lds[16384];
    char* Ab = lds;          // 64x64 bf16 (swizzled)
    char* Bb = lds + 8192;   // 64x64 bf16 (swizzled)

    const int z = blockIdx.z;
    const float* X    = (z == 0) ? qin : (z == 1) ? kin : vin;
    const float* W    = (z == 0) ? Wq  : (z == 1) ? Wk  : Wv;
    const float* bias = (z == 0) ? bq  : (z == 1) ? bk  : bv;
    __bf16* out       = (z == 0) ? qo  : (z == 1) ? ko  : vo;

    const int m0 = blockIdx.x * 64;
    const int n0 = blockIdx.y * 64;
    const int tid  = threadIdx.x;
    const int w    = tid >> 6;
    const int lane = tid & 63;
    const int lrow = lane & 15;
    const int lgrp = lane >> 4;

    f32x4 acc[4] = {};

    const int r  = tid >> 2;          // staging row 0..63
    const int c0 = (tid & 3) * 16;    // staging col start (elements)

    for (int kt = 0; kt < 8; ++kt) {
        const int k0 = kt * 64;
        const float* gA = X + (size_t)(m0 + r) * DMODEL + k0 + c0;
        const float* gB = W + (size_t)(n0 + r) * DMODEL + k0 + c0;
        const int sw = (r & 7) << 4;
#pragma unroll
        for (int i = 0; i < 4; ++i) {
            float4 a4 = *(const float4*)(gA + 4 * i);
            float4 b4 = *(const float4*)(gB + 4 * i);
            bf16x4 av, bv4;
            av[0] = (__bf16)a4.x; av[1] = (__bf16)a4.y; av[2] = (__bf16)a4.z; av[3] = (__bf16)a4.w;
            bv4[0] = (__bf16)b4.x; bv4[1] = (__bf16)b4.y; bv4[2] = (__bf16)b4.z; bv4[3] = (__bf16)b4.w;
            *(bf16x4*)(Ab + r * 128 + ((c0 * 2 + 8 * i) ^ sw)) = av;
            *(bf16x4*)(Bb + r * 128 + ((c0 * 2 + 8 * i) ^ sw)) = bv4;
        }
        __syncthreads();
#pragma unroll
        for (int ks = 0; ks < 2; ++ks) {
            bf16x8 af = *(const bf16x8*)(Ab + (w * 16 + lrow) * 128 +
                                         ((ks * 64 + lgrp * 16) ^ ((lrow & 7) << 4)));
#pragma unroll
            for (int ns = 0; ns < 4; ++ns) {
                bf16x8 bf = *(const bf16x8*)(Bb + (ns * 16 + lrow) * 128 +
                                             ((ks * 64 + lgrp * 16) ^ ((lrow & 7) << 4)));
                acc[ns] = __builtin_amdgcn_mfma_f32_16x16x32_bf16(af, bf, acc[ns], 0, 0, 0);
            }
        }
        __syncthreads();
    }

#pragma unroll
    for (int ns = 0; ns < 4; ++ns) {
        float bcol = bias[n0 + ns * 16 + lrow];
#pragma unroll
        for (int rr = 0; rr < 4; ++rr) {
            int orow = m0 + w * 16 + lgrp * 4 + rr;
            out[(size_t)orow * DMODEL + n0 + ns * 16 + lrow] = (__bf16)(acc[ns][rr] + bcol);
        }
    }
}

// ---------------------------------------------------------------------------
// Kernel 2: attention.  Per workgroup: 64 query rows of one head (4 waves x 16
// rows).  Pass 1: online softmax stats (m,l).  Pass 2: recompute scores, write
// normalized attn (f32) to d_out, accumulate O = P @ V via MFMA.
// ---------------------------------------------------------------------------
__global__ __launch_bounds__(256) void attn_kernel(
    const __bf16* __restrict__ qb, const __bf16* __restrict__ kb,
    const __bf16* __restrict__ vb, const int* __restrict__ mask,
    float* __restrict__ attn_out,   // [NH][T_SEQ][T_SEQ]
    __bf16* __restrict__ ao)        // [T_SEQ][DMODEL]
{
    __shared__ char lds[24576];
    char* Kb = lds;            // K tile 64x64 bf16 swizzled
    char* Vb = lds + 8192;     // V tile transposed: Vt[d][n] swizzled
    char* Pb = lds + 16384;    // P tiles, 2KB per wave

    const int h  = blockIdx.y;
    const int q0 = blockIdx.x * 64;
    const int tid  = threadIdx.x;
    const int w    = tid >> 6;
    const int lane = tid & 63;
    const int lrow = lane & 15;
    const int lgrp = lane >> 4;
    const float SC = 0.125f;  // 1/sqrt(64)

    // Q fragments: rows q0 + w*16 + lrow, k = ks*32 + lgrp*8 + j
    bf16x8 qa[2];
    {
        const __bf16* qp = qb + (size_t)(q0 + w * 16 + lrow) * DMODEL + h * HDIM;
        qa[0] = *(const bf16x8*)(qp + lgrp * 8);
        qa[1] = *(const bf16x8*)(qp + 32 + lgrp * 8);
    }

    float m[4], l[4];
#pragma unroll
    for (int rr = 0; rr < 4; ++rr) { m[rr] = -FLT_MAX; l[rr] = 0.f; }

    // staging indices
    const int srow = tid >> 3;          // K-tile: 0..31 (+32)
    const int scb  = (tid & 7) * 16;    // K-tile: byte col
    const int vn   = tid >> 2;          // V-tile: n 0..63
    const int vd0  = (tid & 3) * 16;    // V-tile: d start

    // ---------------- Pass 1: softmax stats ----------------
    for (int kt = 0; kt < 64; ++kt) {
        {
            const char* gK = (const char*)(kb + (size_t)(kt * 64) * DMODEL + h * HDIM);
#pragma unroll
            for (int i = 0; i < 2; ++i) {
                int r2 = srow + i * 32;
                bf16x8 v = *(const bf16x8*)(gK + (size_t)r2 * (DMODEL * 2) + scb);
                *(bf16x8*)(Kb + r2 * 128 + (scb ^ ((r2 & 7) << 4))) = v;
            }
        }
        __syncthreads();

        f32x4 acc[4] = {};
#pragma unroll
        for (int ns = 0; ns < 4; ++ns)
#pragma unroll
            for (int ks = 0; ks < 2; ++ks) {
                bf16x8 kf = *(const bf16x8*)(Kb + (ns * 16 + lrow) * 128 +
                                             ((ks * 64 + lgrp * 16) ^ ((lrow & 7) << 4)));
                acc[ns] = __builtin_amdgcn_mfma_f32_16x16x32_bf16(qa[ks], kf, acc[ns], 0, 0, 0);
            }

        int mk[4];
#pragma unroll
        for (int ns = 0; ns < 4; ++ns) mk[ns] = mask[kt * 64 + ns * 16 + lrow];

        float s[4][4];
#pragma unroll
        for (int ns = 0; ns < 4; ++ns)
#pragma unroll
            for (int rr = 0; rr < 4; ++rr)
                s[ns][rr] = mk[ns] ? -FLT_MAX : acc[ns][rr] * SC;

#pragma unroll
        for (int rr = 0; rr < 4; ++rr) {
            float mx = fmaxf(fmaxf(s[0][rr], s[1][rr]), fmaxf(s[2][rr], s[3][rr]));
#pragma unroll
            for (int o = 1; o < 16; o <<= 1) mx = fmaxf(mx, __shfl_xor(mx, o));
            float mn = fmaxf(m[rr], mx);
            float sum = __expf(s[0][rr] - mn) + __expf(s[1][rr] - mn) +
                        __expf(s[2][rr] - mn) + __expf(s[3][rr] - mn);
#pragma unroll
            for (int o = 1; o < 16; o <<= 1) sum += __shfl_xor(sum, o);
            l[rr] = l[rr] * __expf(m[rr] - mn) + sum;
            m[rr] = mn;
        }
        __syncthreads();
    }

    float rl[4];
#pragma unroll
    for (int rr = 0; rr < 4; ++rr) rl[rr] = 1.0f / l[rr];

    // ---------------- Pass 2: attn write + PV ----------------
    f32x4 oacc[4] = {};
    float* attn_h = attn_out + (size_t)h * T_SEQ * T_SEQ;
    char* Pw = Pb + w * 2048;

    for (int kt = 0; kt < 64; ++kt) {
        {
            const char* gK = (const char*)(kb + (size_t)(kt * 64) * DMODEL + h * HDIM);
#pragma unroll
            for (int i = 0; i < 2; ++i) {
                int r2 = srow + i * 32;
                bf16x8 v = *(const bf16x8*)(gK + (size_t)r2 * (DMODEL * 2) + scb);
                *(bf16x8*)(Kb + r2 * 128 + (scb ^ ((r2 & 7) << 4))) = v;
            }
            // V transpose-stage: Vt[d][n], swizzle slot = (d ^ (d>>3)) & 7
            const __bf16* gV = vb + (size_t)(kt * 64 + vn) * DMODEL + h * HDIM + vd0;
            bf16x8 v0 = *(const bf16x8*)(gV);
            bf16x8 v1 = *(const bf16x8*)(gV + 8);
#pragma unroll
            for (int dd = 0; dd < 8; ++dd) {
                int d = vd0 + dd;
                *(__bf16*)(Vb + d * 128 + ((vn * 2) ^ (((d ^ (d >> 3)) & 7) << 4))) = v0[dd];
            }
#pragma unroll
            for (int dd = 0; dd < 8; ++dd) {
                int d = vd0 + 8 + dd;
                *(__bf16*)(Vb + d * 128 + ((vn * 2) ^ (((d ^ (d >> 3)) & 7) << 4))) = v1[dd];
            }
        }
        __syncthreads();

        f32x4 acc[4] = {};
#pragma unroll
        for (int ns = 0; ns < 4; ++ns)
#pragma unroll
            for (int ks = 0; ks < 2; ++ks) {
                bf16x8 kf = *(const bf16x8*)(Kb + (ns * 16 + lrow) * 128 +
                                             ((ks * 64 + lgrp * 16) ^ ((lrow & 7) << 4)));
                acc[ns] = __builtin_amdgcn_mfma_f32_16x16x32_bf16(qa[ks], kf, acc[ns], 0, 0, 0);
            }

        // normalized P: write attn (f32, global) + P (bf16, LDS)
#pragma unroll
        for (int ns = 0; ns < 4; ++ns) {
            int mkv = mask[kt * 64 + ns * 16 + lrow];
#pragma unroll
            for (int rr = 0; rr < 4; ++rr) {
                float sv = mkv ? -FLT_MAX : acc[ns][rr] * SC;
                float p = __expf(sv - m[rr]) * rl[rr];
                int prow = lgrp * 4 + rr;
                attn_h[(size_t)(q0 + w * 16 + prow) * T_SEQ + kt * 64 + ns * 16 + lrow] = p;
                *(__bf16*)(Pw + prow * 128 + ((ns * 32 + lrow * 2) ^ ((prow & 7) << 4))) = (__bf16)p;
            }
        }

        // O += P @ V    (A = P from own wave's LDS region; DS ops in-order per wave)
#pragma unroll
        for (int ks = 0; ks < 2; ++ks) {
            bf16x8 pa = *(const bf16x8*)(Pw + lrow * 128 +
                                         ((ks * 64 + lgrp * 16) ^ ((lrow & 7) << 4)));
#pragma unroll
            for (int ds_ = 0; ds_ < 4; ++ds_) {
                int d = ds_ * 16 + lrow;
                bf16x8 vf = *(const bf16x8*)(Vb + d * 128 +
                                             ((ks * 64 + lgrp * 16) ^ (((d ^ (d >> 3)) & 7) << 4)));
                oacc[ds_] = __builtin_amdgcn_mfma_f32_16x16x32_bf16(pa, vf, oacc[ds_], 0, 0, 0);
            }
        }
        __syncthreads();
    }

    // epilogue: attention-out (bf16) for the output projection
#pragma unroll
    for (int ds_ = 0; ds_ < 4; ++ds_) {
#pragma unroll
        for (int rr = 0; rr < 4; ++rr) {
            int orow = q0 + w * 16 + lgrp * 4 + rr;
            ao[(size_t)orow * DMODEL + h * HDIM + ds_ * 16 + lrow] = (__bf16)oacc[ds_][rr];
        }
    }
}

// ---------------------------------------------------------------------------
// Kernel 3: output projection.  out = AO @ Wo^T + bo  (f32 out)
// ---------------------------------------------------------------------------
__global__ __launch_bounds__(256) void oproj_kernel(
    const __bf16* __restrict__ ao, const float* __restrict__ Wo,
    const float* __restrict__ bo, float* __restrict__ out)
{
    __shared__ char lds[16384];
    char* Ab = lds;
    char* Bb = lds + 8192;

    const int m0 = blockIdx.x * 64;
    const int n0 = blockIdx.y * 64;
    const int tid  = threadIdx.x;
    const int w    = tid >> 6;
    const int lane = tid & 63;
    const int lrow = lane & 15;
    const int lgrp = lane >> 4;

    f32x4 acc[4] = {};
    const int r  = tid >> 2;
    const int c0 = (tid & 3) * 16;

    for (int kt = 0; kt < 8; ++kt) {
        const int k0 = kt * 64;
        const int sw = (r & 7) << 4;
        const __bf16* gA = ao + (size_t)(m0 + r) * DMODEL + k0 + c0;
        bf16x8 a0 = *(const bf16x8*)(gA);
        bf16x8 a1 = *(const bf16x8*)(gA + 8);
        *(bf16x8*)(Ab + r * 128 + ((c0 * 2) ^ sw)) = a0;
        *(bf16x8*)(Ab + r * 128 + ((c0 * 2 + 16) ^ sw)) = a1;
        const float* gB = Wo + (size_t)(n0 + r) * DMODEL + k0 + c0;
#pragma unroll
        for (int i = 0; i < 4; ++i) {
            float4 b4 = *(const float4*)(gB + 4 * i);
            bf16x4 bv4;
            bv4[0] = (__bf16)b4.x; bv4[1] = (__bf16)b4.y; bv4[2] = (__bf16)b4.z; bv4[3] = (__bf16)b4.w;
            *(bf16x4*)(Bb + r * 128 + ((c0 * 2 + 8 * i) ^ sw)) = bv4;
        }
        __syncthreads();
#pragma unroll
        for (int ks = 0; ks < 2; ++ks) {
            bf16x8 af = *(const bf16x8*)(Ab + (w * 16 + lrow) * 128 +
                                         ((ks * 64 + lgrp * 16) ^ ((lrow & 7) << 4)));
#pragma unroll
            for (int ns = 0; ns < 4; ++ns) {
                bf16x8 bf = *(const bf16x8*)(Bb + (ns * 16 + lrow) * 128 +
                                             ((ks * 64 + lgrp * 16) ^ ((lrow & 7) << 4)));
                acc[ns] = __builtin_amdgcn_mfma_f32_16x16x32_bf16(af, bf, acc[ns], 0, 0, 0);
            }
        }
        __syncthreads();
    }

#pragma unroll
    for (int ns = 0; ns < 4; ++ns) {
        float bcol = bo[n0 + ns * 16 + lrow];
#pragma unroll
        for (int rr = 0; rr < 4; ++rr) {
            int orow = m0 + w * 16 + lgrp * 4 + rr;
            out[(size_t)orow * DMODEL + n0 + ns * 16 + lrow] = acc[ns][rr] + bcol;
        }
    }
}

// ---------------------------------------------------------------------------
extern "C" void kernel_launch(void* const* d_in, const int* in_sizes, int n_in,
                              void* d_out, int out_size, void* d_ws, size_t ws_size,
                              hipStream_t stream) {
    const float* query = (const float*)d_in[0];
    const float* key   = (const float*)d_in[1];
    const float* value = (const float*)d_in[2];
    const int*   mask  = (const int*)d_in[3];
    const float* Wq = (const float*)d_in[4];
    const float* bq = (const float*)d_in[5];
    const float* Wk = (const float*)d_in[6];
    const float* bk = (const float*)d_in[7];
    const float* Wv = (const float*)d_in[8];
    const float* bv = (const float*)d_in[9];
    const float* Wo = (const float*)d_in[10];
    const float* bo = (const float*)d_in[11];

    float* out  = (float*)d_out;
    float* attn = out + (size_t)T_SEQ * DMODEL;   // 2097152 floats of `out` first

    char* ws = (char*)d_ws;
    __bf16* qo = (__bf16*)(ws);
    __bf16* ko = (__bf16*)(ws + 4 * 1024 * 1024);
    __bf16* vo = (__bf16*)(ws + 8 * 1024 * 1024);
    __bf16* ao = (__bf16*)(ws + 12 * 1024 * 1024);

    qkv_kernel<<<dim3(64, 8, 3), 256, 0, stream>>>(query, key, value,
                                                   Wq, bq, Wk, bk, Wv, bv, qo, ko, vo);
    attn_kernel<<<dim3(64, 8), 256, 0, stream>>>(qo, ko, vo, mask, attn, ao);
    oproj_kernel<<<dim3(64, 8), 256, 0, stream>>>(ao, Wo, bo, out);
}

// Round 2
// 249.971 us; speedup vs baseline: 1.7852x; 1.7852x over previous
//
#include <hip/hip_runtime.h>
#include <hip/hip_bf16.h>
#include <float.h>
#include <stdint.h>

typedef __bf16 bf16x8 __attribute__((ext_vector_type(8)));
typedef __bf16 bf16x4 __attribute__((ext_vector_type(4)));
typedef float  f32x4  __attribute__((ext_vector_type(4)));

#define T_SEQ 4096
#define DMODEL 512
#define NH 8
#define HDIM 64
#define KS1 4                       // k-splits in stats pass
#define L2E 1.44269504088896340736f

__device__ __forceinline__ float fexp2(float x) { return __builtin_amdgcn_exp2f(x); }

// async global->LDS, 16B per lane.  LDS dest is wave-uniform base + lane*16;
// global source is per-lane (pre-swizzled so linear LDS slots get swizzled data).
__device__ __forceinline__ void gl_lds16(const __bf16* g, char* l) {
    __builtin_amdgcn_global_load_lds(
        (const __attribute__((address_space(1))) unsigned int*)(g),
        (__attribute__((address_space(3))) unsigned int*)(l),
        16, 0, 0);
}

// granule swizzle for 16-row P tiles: distinct granule-PAIRS per lgrp stripe
__device__ __forceinline__ int gswP(int r) { return (r & 7) ^ ((r >> 3) << 1); }

// ---------------------------------------------------------------------------
// Kernel 1: fused QKV projection.  q scaled by 1/8; V written TRANSPOSED
// (vt[feature][seq]) for pass-2 staging.
// ---------------------------------------------------------------------------
__global__ __launch_bounds__(256) void qkv_kernel(
    const float* __restrict__ qin, const float* __restrict__ kin, const float* __restrict__ vin,
    const float* __restrict__ Wq, const float* __restrict__ bq,
    const float* __restrict__ Wk, const float* __restrict__ bk,
    const float* __restrict__ Wv, const float* __restrict__ bv,
    __bf16* __restrict__ qo, __bf16* __restrict__ ko, __bf16* __restrict__ vt)
{
    __shared__ char lds[16384];
    char* Ab = lds;
    char* Bb = lds + 8192;

    const int z = blockIdx.z;
    const float* X    = (z == 0) ? qin : (z == 1) ? kin : vin;
    const float* W    = (z == 0) ? Wq  : (z == 1) ? Wk  : Wv;
    const float* bias = (z == 0) ? bq  : (z == 1) ? bk  : bv;

    const int m0 = blockIdx.x * 64;
    const int n0 = blockIdx.y * 64;
    const int tid  = threadIdx.x;
    const int w    = tid >> 6;
    const int lane = tid & 63;
    const int lrow = lane & 15;
    const int lgrp = lane >> 4;

    f32x4 acc[4] = {};
    const int r  = tid >> 2;
    const int c0 = (tid & 3) * 16;

    for (int kt = 0; kt < 8; ++kt) {
        const int k0 = kt * 64;
        const float* gA = X + (size_t)(m0 + r) * DMODEL + k0 + c0;
        const float* gB = W + (size_t)(n0 + r) * DMODEL + k0 + c0;
        const int sw = (r & 7) << 4;
#pragma unroll
        for (int i = 0; i < 4; ++i) {
            float4 a4 = *(const float4*)(gA + 4 * i);
            float4 b4 = *(const float4*)(gB + 4 * i);
            bf16x4 av, bv4;
            av[0] = (__bf16)a4.x; av[1] = (__bf16)a4.y; av[2] = (__bf16)a4.z; av[3] = (__bf16)a4.w;
            bv4[0] = (__bf16)b4.x; bv4[1] = (__bf16)b4.y; bv4[2] = (__bf16)b4.z; bv4[3] = (__bf16)b4.w;
            *(bf16x4*)(Ab + r * 128 + ((c0 * 2 + 8 * i) ^ sw)) = av;
            *(bf16x4*)(Bb + r * 128 + ((c0 * 2 + 8 * i) ^ sw)) = bv4;
        }
        __syncthreads();
#pragma unroll
        for (int ks = 0; ks < 2; ++ks) {
            bf16x8 af = *(const bf16x8*)(Ab + (w * 16 + lrow) * 128 +
                                         ((ks * 64 + lgrp * 16) ^ ((lrow & 7) << 4)));
#pragma unroll
            for (int ns = 0; ns < 4; ++ns) {
                bf16x8 bf = *(const bf16x8*)(Bb + (ns * 16 + lrow) * 128 +
                                             ((ks * 64 + lgrp * 16) ^ ((lrow & 7) << 4)));
                acc[ns] = __builtin_amdgcn_mfma_f32_16x16x32_bf16(af, bf, acc[ns], 0, 0, 0);
            }
        }
        __syncthreads();
    }

    if (z == 2) {
        // transpose epilogue via LDS: LT[col][row], granule swizzle on col
        char* LT = lds;
#pragma unroll
        for (int ns = 0; ns < 4; ++ns) {
            float bcol = bias[n0 + ns * 16 + lrow];
#pragma unroll
            for (int rr = 0; rr < 4; ++rr) {
                int col = ns * 16 + lrow;
                int row = w * 16 + lgrp * 4 + rr;
                *(__bf16*)(LT + col * 128 + ((row * 2) ^ ((col & 7) << 4))) =
                    (__bf16)(acc[ns][rr] + bcol);
            }
        }
        __syncthreads();
        int d  = tid >> 2;
        int nb = (tid & 3) * 32;
        bf16x8 t0 = *(const bf16x8*)(LT + d * 128 + (nb ^ ((d & 7) << 4)));
        bf16x8 t1 = *(const bf16x8*)(LT + d * 128 + ((nb + 16) ^ ((d & 7) << 4)));
        __bf16* dst = vt + (size_t)(n0 + d) * T_SEQ + m0 + (tid & 3) * 16;
        *(bf16x8*)dst = t0;
        *(bf16x8*)(dst + 8) = t1;
    } else {
        __bf16* out = (z == 0) ? qo : ko;
        const float sc = (z == 0) ? 0.125f : 1.0f;   // fold 1/sqrt(HD) into Q (exact)
#pragma unroll
        for (int ns = 0; ns < 4; ++ns) {
            float bcol = bias[n0 + ns * 16 + lrow];
#pragma unroll
            for (int rr = 0; rr < 4; ++rr) {
                int orow = m0 + w * 16 + lgrp * 4 + rr;
                out[(size_t)orow * DMODEL + n0 + ns * 16 + lrow] =
                    (__bf16)((acc[ns][rr] + bcol) * sc);
            }
        }
    }
}

// ---------------------------------------------------------------------------
// Kernel 2: softmax denominators.  l_part[h][ksp][q] = sum over k-slice of
// exp(s).  No max tracking (scores bounded), no in-loop cross-lane ops.
// ---------------------------------------------------------------------------
__global__ __launch_bounds__(256) void attn_stats(
    const __bf16* __restrict__ qb, const __bf16* __restrict__ kb,
    const int* __restrict__ mask, float* __restrict__ l_part)
{
    __shared__ char lds[16384];
    char* KB0 = lds;
    char* KB1 = lds + 8192;

    const int b    = blockIdx.x;
    const int rmap = (b & 7) * ((64 * NH * KS1) / 8) + (b >> 3);  // XCD-chunked
    const int qbi  = rmap & 63;
    const int h    = (rmap >> 6) & (NH - 1);
    const int ksp  = rmap >> 9;
    const int q0   = qbi * 64;
    const int k0   = ksp * (T_SEQ / KS1);

    const int tid  = threadIdx.x;
    const int w    = tid >> 6;
    const int lane = tid & 63;
    const int lrow = lane & 15;
    const int lgrp = lane >> 4;

    bf16x8 qa[2];
    {
        const __bf16* qp = qb + (size_t)(q0 + w * 16 + lrow) * DMODEL + h * HDIM;
        qa[0] = *(const bf16x8*)(qp + lgrp * 8);
        qa[1] = *(const bf16x8*)(qp + 32 + lgrp * 8);
    }

    // staging source (pre-swizzled): lane slot -> (key, granule)
    const int key0 = w * 16 + (lane >> 3);
    const int key1 = key0 + 8;
    const int g    = lane & 7;
    const __bf16* sK0 = kb + (size_t)(k0 + key0) * DMODEL + h * HDIM + (g ^ (key0 & 7)) * 8;
    const __bf16* sK1 = kb + (size_t)(k0 + key1) * DMODEL + h * HDIM + (g ^ (key1 & 7)) * 8;
    char* ldsl0 = (char*)0; // silence unused warnings pattern
    (void)ldsl0;

    float lsum[4] = {0.f, 0.f, 0.f, 0.f};

    gl_lds16(sK0, KB0 + w * 2048);
    gl_lds16(sK1, KB0 + w * 2048 + 1024);
    __syncthreads();

    char* cur = KB0;
    char* nxt = KB1;
    const int NT = (T_SEQ / KS1) / 64;   // 16
    for (int kt = 0; kt < NT; ++kt) {
        if (kt + 1 < NT) {
            gl_lds16(sK0 + (size_t)(kt + 1) * 64 * DMODEL, nxt + w * 2048);
            gl_lds16(sK1 + (size_t)(kt + 1) * 64 * DMODEL, nxt + w * 2048 + 1024);
        }
        float mbv[4];
#pragma unroll
        for (int ns = 0; ns < 4; ++ns)
            mbv[ns] = mask[k0 + kt * 64 + ns * 16 + lrow] ? -1e30f : 0.f;

        f32x4 acc[4] = {};
        __builtin_amdgcn_s_setprio(1);
#pragma unroll
        for (int ns = 0; ns < 4; ++ns)
#pragma unroll
            for (int ks = 0; ks < 2; ++ks) {
                bf16x8 kf = *(const bf16x8*)(cur + (ns * 16 + lrow) * 128 +
                                             ((ks * 64 + lgrp * 16) ^ ((lrow & 7) << 4)));
                acc[ns] = __builtin_amdgcn_mfma_f32_16x16x32_bf16(qa[ks], kf, acc[ns], 0, 0, 0);
            }
        __builtin_amdgcn_s_setprio(0);
#pragma unroll
        for (int ns = 0; ns < 4; ++ns)
#pragma unroll
            for (int rr = 0; rr < 4; ++rr)
                lsum[rr] += fexp2(fmaf(acc[ns][rr], L2E, mbv[ns]));
        __syncthreads();
        char* t = cur; cur = nxt; nxt = t;
    }

#pragma unroll
    for (int rr = 0; rr < 4; ++rr) {
        float v = lsum[rr];
        v += __shfl_xor(v, 1); v += __shfl_xor(v, 2);
        v += __shfl_xor(v, 4); v += __shfl_xor(v, 8);
        lsum[rr] = v;
    }
    if (lrow == 0) {
#pragma unroll
        for (int rr = 0; rr < 4; ++rr)
            l_part[((size_t)h * KS1 + ksp) * T_SEQ + q0 + w * 16 + lgrp * 4 + rr] = lsum[rr];
    }
}

// ---------------------------------------------------------------------------
// Kernel 3: main attention pass.  Recompute QK^T, write normalized attn (f32),
// accumulate O = P @ V.  K-split KSP2 with f32 O-partials (or bf16 fallback).
// ---------------------------------------------------------------------------
__global__ __launch_bounds__(256) void attn_main(
    const __bf16* __restrict__ qb, const __bf16* __restrict__ kb,
    const __bf16* __restrict__ vt, const int* __restrict__ mask,
    const float* __restrict__ l_part,
    float* __restrict__ attn_out, void* __restrict__ opart,
    int KSP2, int of32)
{
    __shared__ char lds[40960];
    char* KB0 = lds;
    char* KB1 = lds + 8192;
    char* VB0 = lds + 16384;
    char* VB1 = lds + 24576;
    char* PB  = lds + 32768;   // 4 waves x 2 KB

    const int nwg  = 64 * NH * KSP2;
    const int b    = blockIdx.x;
    const int rmap = (b & 7) * (nwg >> 3) + (b >> 3);   // XCD-chunked (nwg%8==0)
    const int qbi  = rmap & 63;
    const int h    = (rmap >> 6) & (NH - 1);
    const int kz   = rmap >> 9;
    const int q0   = qbi * 64;
    const int kspan = T_SEQ / KSP2;
    const int k0   = kz * kspan;
    const int NT   = kspan / 64;

    const int tid  = threadIdx.x;
    const int w    = tid >> 6;
    const int lane = tid & 63;
    const int lrow = lane & 15;
    const int lgrp = lane >> 4;

    bf16x8 qa[2];
    {
        const __bf16* qp = qb + (size_t)(q0 + w * 16 + lrow) * DMODEL + h * HDIM;
        qa[0] = *(const bf16x8*)(qp + lgrp * 8);
        qa[1] = *(const bf16x8*)(qp + 32 + lgrp * 8);
    }

    float rl[4];
#pragma unroll
    for (int rr = 0; rr < 4; ++rr) {
        float s = 0.f;
#pragma unroll
        for (int ks = 0; ks < KS1; ++ks)
            s += l_part[((size_t)h * KS1 + ks) * T_SEQ + q0 + w * 16 + lgrp * 4 + rr];
        rl[rr] = 1.0f / s;
    }

    // staging sources (pre-swizzled)
    const int key0 = w * 16 + (lane >> 3);
    const int key1 = key0 + 8;
    const int g    = lane & 7;
    const __bf16* sK0 = kb + (size_t)(k0 + key0) * DMODEL + h * HDIM + (g ^ (key0 & 7)) * 8;
    const __bf16* sK1 = kb + (size_t)(k0 + key1) * DMODEL + h * HDIM + (g ^ (key1 & 7)) * 8;
    const __bf16* sV0 = vt + (size_t)(h * HDIM + key0) * T_SEQ + k0 + (g ^ (key0 & 7)) * 8;
    const __bf16* sV1 = vt + (size_t)(h * HDIM + key1) * T_SEQ + k0 + (g ^ (key1 & 7)) * 8;

    f32x4 oacc[4] = {};
    float* attn_h = attn_out + (size_t)h * T_SEQ * T_SEQ;
    char* Pw = PB + w * 2048;
    const int gswl = gswP(lrow);

    gl_lds16(sK0, KB0 + w * 2048);
    gl_lds16(sK1, KB0 + w * 2048 + 1024);
    gl_lds16(sV0, VB0 + w * 2048);
    gl_lds16(sV1, VB0 + w * 2048 + 1024);
    __syncthreads();

    char *kc = KB0, *kn = KB1, *vc = VB0, *vn = VB1;
    for (int kt = 0; kt < NT; ++kt) {
        if (kt + 1 < NT) {
            gl_lds16(sK0 + (size_t)(kt + 1) * 64 * DMODEL, kn + w * 2048);
            gl_lds16(sK1 + (size_t)(kt + 1) * 64 * DMODEL, kn + w * 2048 + 1024);
            gl_lds16(sV0 + (size_t)(kt + 1) * 64,          vn + w * 2048);
            gl_lds16(sV1 + (size_t)(kt + 1) * 64,          vn + w * 2048 + 1024);
        }
        float mbv[4];
#pragma unroll
        for (int ns = 0; ns < 4; ++ns)
            mbv[ns] = mask[k0 + kt * 64 + ns * 16 + lrow] ? -1e30f : 0.f;

        f32x4 acc[4] = {};
        __builtin_amdgcn_s_setprio(1);
#pragma unroll
        for (int ns = 0; ns < 4; ++ns)
#pragma unroll
            for (int ks = 0; ks < 2; ++ks) {
                bf16x8 kf = *(const bf16x8*)(kc + (ns * 16 + lrow) * 128 +
                                             ((ks * 64 + lgrp * 16) ^ ((lrow & 7) << 4)));
                acc[ns] = __builtin_amdgcn_mfma_f32_16x16x32_bf16(qa[ks], kf, acc[ns], 0, 0, 0);
            }
        __builtin_amdgcn_s_setprio(0);

        // normalized P -> attn (f32 global) + P (bf16 LDS)
#pragma unroll
        for (int ns = 0; ns < 4; ++ns) {
#pragma unroll
            for (int rr = 0; rr < 4; ++rr) {
                float p = fexp2(fmaf(acc[ns][rr], L2E, mbv[ns])) * rl[rr];
                int prow = lgrp * 4 + rr;
                attn_h[(size_t)(q0 + w * 16 + prow) * T_SEQ + k0 + kt * 64 + ns * 16 + lrow] = p;
                *(__bf16*)(Pw + prow * 128 + ((ns * 32 + lrow * 2) ^ (gswP(prow) << 4))) = (__bf16)p;
            }
        }

        // O += P @ V
        __builtin_amdgcn_s_setprio(1);
#pragma unroll
        for (int ks = 0; ks < 2; ++ks) {
            bf16x8 pa = *(const bf16x8*)(Pw + lrow * 128 + ((ks * 64 + lgrp * 16) ^ (gswl << 4)));
#pragma unroll
            for (int dsb = 0; dsb < 4; ++dsb) {
                int d = dsb * 16 + lrow;
                bf16x8 vf = *(const bf16x8*)(vc + d * 128 +
                                             ((ks * 64 + lgrp * 16) ^ ((d & 7) << 4)));
                oacc[dsb] = __builtin_amdgcn_mfma_f32_16x16x32_bf16(pa, vf, oacc[dsb], 0, 0, 0);
            }
        }
        __builtin_amdgcn_s_setprio(0);

        __syncthreads();
        char* t;
        t = kc; kc = kn; kn = t;
        t = vc; vc = vn; vn = t;
    }

    if (of32) {
        float* op = (float*)opart + (size_t)kz * T_SEQ * DMODEL;
#pragma unroll
        for (int dsb = 0; dsb < 4; ++dsb)
#pragma unroll
            for (int rr = 0; rr < 4; ++rr)
                op[(size_t)(q0 + w * 16 + lgrp * 4 + rr) * DMODEL + h * HDIM + dsb * 16 + lrow] =
                    oacc[dsb][rr];
    } else {
        __bf16* op = (__bf16*)opart;
#pragma unroll
        for (int dsb = 0; dsb < 4; ++dsb)
#pragma unroll
            for (int rr = 0; rr < 4; ++rr)
                op[(size_t)(q0 + w * 16 + lgrp * 4 + rr) * DMODEL + h * HDIM + dsb * 16 + lrow] =
                    (__bf16)oacc[dsb][rr];
    }
}

// ---------------------------------------------------------------------------
// Kernel 4: output projection.  out = (sum of O partials) @ Wo^T + bo
// ---------------------------------------------------------------------------
__global__ __launch_bounds__(256) void oproj_kernel(
    const void* __restrict__ opart, const float* __restrict__ Wo,
    const float* __restrict__ bo, float* __restrict__ out, int KSP2, int of32)
{
    __shared__ char lds[16384];
    char* Ab = lds;
    char* Bb = lds + 8192;

    const int m0 = blockIdx.x * 64;
    const int n0 = blockIdx.y * 64;
    const int tid  = threadIdx.x;
    const int w    = tid >> 6;
    const int lane = tid & 63;
    const int lrow = lane & 15;
    const int lgrp = lane >> 4;

    f32x4 acc[4] = {};
    const int r   = tid >> 2;
    const int c0e = (tid & 3) * 16;
    const int sw  = (r & 7) << 4;

    for (int kt = 0; kt < 8; ++kt) {
        const int k0 = kt * 64;
        if (of32) {
            const float* p0 = (const float*)opart + (size_t)(m0 + r) * DMODEL + k0 + c0e;
            const float* p1 = p0 + (size_t)T_SEQ * DMODEL;
#pragma unroll
            for (int i = 0; i < 4; ++i) {
                f32x4 a4 = *(const f32x4*)(p0 + 4 * i);
                if (KSP2 == 2) a4 = a4 + *(const f32x4*)(p1 + 4 * i);
                bf16x4 av;
                av[0] = (__bf16)a4[0]; av[1] = (__bf16)a4[1];
                av[2] = (__bf16)a4[2]; av[3] = (__bf16)a4[3];
                *(bf16x4*)(Ab + r * 128 + ((c0e * 2 + 8 * i) ^ sw)) = av;
            }
        } else {
            const __bf16* pa = (const __bf16*)opart + (size_t)(m0 + r) * DMODEL + k0 + c0e;
            bf16x8 a0 = *(const bf16x8*)pa;
            bf16x8 a1 = *(const bf16x8*)(pa + 8);
            *(bf16x8*)(Ab + r * 128 + ((c0e * 2) ^ sw)) = a0;
            *(bf16x8*)(Ab + r * 128 + ((c0e * 2 + 16) ^ sw)) = a1;
        }
        const float* gB = Wo + (size_t)(n0 + r) * DMODEL + k0 + c0e;
#pragma unroll
        for (int i = 0; i < 4; ++i) {
            float4 b4 = *(const float4*)(gB + 4 * i);
            bf16x4 bv4;
            bv4[0] = (__bf16)b4.x; bv4[1] = (__bf16)b4.y;
            bv4[2] = (__bf16)b4.z; bv4[3] = (__bf16)b4.w;
            *(bf16x4*)(Bb + r * 128 + ((c0e * 2 + 8 * i) ^ sw)) = bv4;
        }
        __syncthreads();
#pragma unroll
        for (int ks = 0; ks < 2; ++ks) {
            bf16x8 af = *(const bf16x8*)(Ab + (w * 16 + lrow) * 128 +
                                         ((ks * 64 + lgrp * 16) ^ ((lrow & 7) << 4)));
#pragma unroll
            for (int ns = 0; ns < 4; ++ns) {
                bf16x8 bf = *(const bf16x8*)(Bb + (ns * 16 + lrow) * 128 +
                                             ((ks * 64 + lgrp * 16) ^ ((lrow & 7) << 4)));
                acc[ns] = __builtin_amdgcn_mfma_f32_16x16x32_bf16(af, bf, acc[ns], 0, 0, 0);
            }
        }
        __syncthreads();
    }

#pragma unroll
    for (int ns = 0; ns < 4; ++ns) {
        float bcol = bo[n0 + ns * 16 + lrow];
#pragma unroll
        for (int rr = 0; rr < 4; ++rr) {
            int orow = m0 + w * 16 + lgrp * 4 + rr;
            out[(size_t)orow * DMODEL + n0 + ns * 16 + lrow] = acc[ns][rr] + bcol;
        }
    }
}

// ---------------------------------------------------------------------------
extern "C" void kernel_launch(void* const* d_in, const int* in_sizes, int n_in,
                              void* d_out, int out_size, void* d_ws, size_t ws_size,
                              hipStream_t stream) {
    const float* query = (const float*)d_in[0];
    const float* key   = (const float*)d_in[1];
    const float* value = (const float*)d_in[2];
    const int*   mask  = (const int*)d_in[3];
    const float* Wq = (const float*)d_in[4];
    const float* bq = (const float*)d_in[5];
    const float* Wk = (const float*)d_in[6];
    const float* bk = (const float*)d_in[7];
    const float* Wv = (const float*)d_in[8];
    const float* bv = (const float*)d_in[9];
    const float* Wo = (const float*)d_in[10];
    const float* bo = (const float*)d_in[11];

    float* out  = (float*)d_out;
    float* attn = out + (size_t)T_SEQ * DMODEL;

    char* ws = (char*)d_ws;
    __bf16* qo     = (__bf16*)(ws);
    __bf16* ko     = (__bf16*)(ws + (4u << 20));
    __bf16* vt     = (__bf16*)(ws + (8u << 20));
    float*  l_part = (float*)(ws + (12u << 20));                  // 512 KB
    void*   opart  = (void*)(ws + (12u << 20) + (1u << 19));
    const size_t obase = (12u << 20) + (1u << 19);

    int KSP2, of32;
    const size_t oslice = (size_t)T_SEQ * DMODEL * 4;             // 8 MB f32
    if (ws_size >= obase + 2 * oslice)      { KSP2 = 2; of32 = 1; }
    else if (ws_size >= obase + oslice)     { KSP2 = 1; of32 = 1; }
    else                                    { KSP2 = 1; of32 = 0; }

    qkv_kernel<<<dim3(64, 8, 3), 256, 0, stream>>>(query, key, value,
                                                   Wq, bq, Wk, bk, Wv, bv, qo, ko, vt);
    attn_stats<<<dim3(64 * NH * KS1), 256, 0, stream>>>(qo, ko, mask, l_part);
    attn_main<<<dim3(64 * NH * KSP2), 256, 0, stream>>>(qo, ko, vt, mask, l_part,
                                                        attn, opart, KSP2, of32);
    oproj_kernel<<<dim3(64, 8), 256, 0, stream>>>(opart, Wo, bo, out, KSP2, of32);
}